// Round 1
// baseline (26954.874 us; speedup 1.0000x reference)
//
#include <hip/hip_runtime.h>
#include <cstddef>

// Problem constants (match reference)
#define NS   16384
#define HS   512
#define DS   128
#define KOBS 40
#define ES   4096
#define DTC  0.05f

// Tiling: 64x64 block tile, 256 threads, 4x4 microtile per thread, K-tile 16.
#define LDSS 20   // LDS row stride (floats), multiple of 4 for float4, breaks pow2 conflicts

// ---------------------------------------------------------------------------
// Core: acc[4][4] += A[row0+.. (optionally gathered)][k] * W[col0+..][k]
// A is [rows, lda] row-major (k contiguous); W is [cols, ldw] row-major.
// ---------------------------------------------------------------------------
__device__ __forceinline__ void gemm_core(
    float acc[4][4],
    const float* __restrict__ A, int lda,
    const int* __restrict__ idx, int row0,
    const float* __restrict__ W, int ldw, int col0,
    int Kdim, float* As, float* Ws)
{
  const int tid  = threadIdx.x;
  const int lrow = tid >> 2;          // 0..63 : tile row being staged
  const int kq   = (tid & 3) << 2;    // 0,4,8,12 : k-quad within tile
  int arow = row0 + lrow;
  if (idx) arow = idx[arow];
  const float* Ap = A + (size_t)arow * lda + kq;
  const float* Wp = W + (size_t)(col0 + lrow) * ldw + kq;
  const int tx = tid & 15, ty = tid >> 4;

  for (int k0 = 0; k0 < Kdim; k0 += 16) {
    const float4 av = *(const float4*)(Ap + k0);
    const float4 wv = *(const float4*)(Wp + k0);
    __syncthreads();                       // protect previous iteration reads
    *(float4*)(As + lrow * LDSS + kq) = av;
    *(float4*)(Ws + lrow * LDSS + kq) = wv;
    __syncthreads();
#pragma unroll
    for (int kg = 0; kg < 4; ++kg) {
      float4 aa[4], ww[4];
#pragma unroll
      for (int i = 0; i < 4; ++i)
        aa[i] = *(const float4*)(As + (ty + 16 * i) * LDSS + kg * 4);
#pragma unroll
      for (int j = 0; j < 4; ++j)
        ww[j] = *(const float4*)(Ws + (tx + 16 * j) * LDSS + kg * 4);
      const float* af = (const float*)aa;
      const float* wf = (const float*)ww;
#pragma unroll
      for (int i = 0; i < 4; ++i)
#pragma unroll
        for (int j = 0; j < 4; ++j)
#pragma unroll
          for (int kk = 0; kk < 4; ++kk)
            acc[i][j] += af[i * 4 + kk] * wf[j * 4 + kk];
    }
  }
}

// ---------------------------------------------------------------------------
// Kernels
// ---------------------------------------------------------------------------

// tmp = tanh(h @ Wo1^T + bo1)   (rows NS, K = HS, cols HS)
__global__ __launch_bounds__(256) void k_gemm_tanh(
    const float* __restrict__ A, const float* __restrict__ W,
    const float* __restrict__ bias, float* __restrict__ out)
{
  __shared__ float As[64 * LDSS], Ws[64 * LDSS];
  float acc[4][4] = {};
  const int row0 = blockIdx.x * 64, col0 = blockIdx.y * 64;
  gemm_core(acc, A, HS, nullptr, row0, W, HS, col0, HS, As, Ws);
  const int tx = threadIdx.x & 15, ty = threadIdx.x >> 4;
#pragma unroll
  for (int i = 0; i < 4; ++i) {
    const int r = row0 + ty + 16 * i;
#pragma unroll
    for (int j = 0; j < 4; ++j) {
      const int c = col0 + tx + 16 * j;
      out[(size_t)r * HS + c] = tanhf(acc[i][j] + bias[c]);
    }
  }
}

// h = h + DT * (tmp @ Wo2^T + bo2)
__global__ __launch_bounds__(256) void k_gemm_resid(
    const float* __restrict__ A, const float* __restrict__ W,
    const float* __restrict__ bias, float* __restrict__ h)
{
  __shared__ float As[64 * LDSS], Ws[64 * LDSS];
  float acc[4][4] = {};
  const int row0 = blockIdx.x * 64, col0 = blockIdx.y * 64;
  gemm_core(acc, A, HS, nullptr, row0, W, HS, col0, HS, As, Ws);
  const int tx = threadIdx.x & 15, ty = threadIdx.x >> 4;
#pragma unroll
  for (int i = 0; i < 4; ++i) {
    const int r = row0 + ty + 16 * i;
#pragma unroll
    for (int j = 0; j < 4; ++j) {
      const int c = col0 + tx + 16 * j;
      const size_t o = (size_t)r * HS + c;
      h[o] = h[o] + DTC * (acc[i][j] + bias[c]);
    }
  }
}

// tmpE = relu(h[idx] @ Wp1^T + bp1)   (rows ES, K = HS, cols HS)
__global__ __launch_bounds__(256) void k_gemm_relu_gather(
    const float* __restrict__ h, const int* __restrict__ idx,
    const float* __restrict__ W, const float* __restrict__ bias,
    float* __restrict__ out)
{
  __shared__ float As[64 * LDSS], Ws[64 * LDSS];
  float acc[4][4] = {};
  const int row0 = blockIdx.x * 64, col0 = blockIdx.y * 64;
  gemm_core(acc, h, HS, idx, row0, W, HS, col0, HS, As, Ws);
  const int tx = threadIdx.x & 15, ty = threadIdx.x >> 4;
#pragma unroll
  for (int i = 0; i < 4; ++i) {
    const int r = row0 + ty + 16 * i;
#pragma unroll
    for (int j = 0; j < 4; ++j) {
      const int c = col0 + tx + 16 * j;
      const float v = acc[i][j] + bias[c];
      out[(size_t)r * HS + c] = v > 0.f ? v : 0.f;
    }
  }
}

// p = tmpE @ Wp2^T + bp2 ; loss += sum |X - p| * M   (rows ES, K = HS, cols DS)
__global__ __launch_bounds__(256) void k_gemm_loss(
    const float* __restrict__ A, const float* __restrict__ W,
    const float* __restrict__ bias, const float* __restrict__ X,
    const float* __restrict__ Mm, float* __restrict__ accum)
{
  __shared__ float As[64 * LDSS], Ws[64 * LDSS];
  __shared__ float red[256];
  float acc[4][4] = {};
  const int row0 = blockIdx.x * 64, col0 = blockIdx.y * 64;
  gemm_core(acc, A, HS, nullptr, row0, W, HS, col0, HS, As, Ws);
  const int tx = threadIdx.x & 15, ty = threadIdx.x >> 4;
  float ls = 0.f;
#pragma unroll
  for (int i = 0; i < 4; ++i) {
    const int r = row0 + ty + 16 * i;
#pragma unroll
    for (int j = 0; j < 4; ++j) {
      const int c = col0 + tx + 16 * j;
      const float p = acc[i][j] + bias[c];
      const size_t o = (size_t)r * DS + c;
      ls += fabsf(X[o] - p) * Mm[o];
    }
  }
  red[threadIdx.x] = ls;
  __syncthreads();
  for (int s = 128; s > 0; s >>= 1) {
    if (threadIdx.x < s) red[threadIdx.x] += red[threadIdx.x + s];
    __syncthreads();
  }
  if (threadIdx.x == 0) atomicAdd(accum, red[0]);
}

// hnewE = tanh(Xk @ W_ih^T + b_ih + h[idx] @ W_hh^T + b_hh)   (rows ES, cols HS)
__global__ __launch_bounds__(256) void k_gemm_rnn(
    const float* __restrict__ Xk, const float* __restrict__ h,
    const int* __restrict__ idx,
    const float* __restrict__ W_ih, const float* __restrict__ b_ih,
    const float* __restrict__ W_hh, const float* __restrict__ b_hh,
    float* __restrict__ outE)
{
  __shared__ float As[64 * LDSS], Ws[64 * LDSS];
  float acc[4][4] = {};
  const int row0 = blockIdx.x * 64, col0 = blockIdx.y * 64;
  gemm_core(acc, Xk, DS, nullptr, row0, W_ih, DS, col0, DS, As, Ws);
  gemm_core(acc, h, HS, idx, row0, W_hh, HS, col0, HS, As, Ws);
  const int tx = threadIdx.x & 15, ty = threadIdx.x >> 4;
#pragma unroll
  for (int i = 0; i < 4; ++i) {
    const int r = row0 + ty + 16 * i;
#pragma unroll
    for (int j = 0; j < 4; ++j) {
      const int c = col0 + tx + 16 * j;
      outE[(size_t)r * HS + c] = tanhf(acc[i][j] + b_ih[c] + b_hh[c]);
    }
  }
}

// h[idx[r], :] = src[r, :]
__global__ void k_scatter(float* __restrict__ h, const float* __restrict__ src,
                          const int* __restrict__ idx)
{
  const int t  = blockIdx.x * blockDim.x + threadIdx.x;  // over ES*HS/4
  const int r  = t / (HS / 4);
  const int c4 = (t % (HS / 4)) * 4;
  const int gr = idx[r];
  *(float4*)(h + (size_t)gr * HS + c4) = *(const float4*)(src + (size_t)r * HS + c4);
}

__global__ void k_zero(float* __restrict__ p, size_t n4)
{
  size_t i = (size_t)blockIdx.x * blockDim.x + threadIdx.x;
  const size_t st = (size_t)gridDim.x * blockDim.x;
  const float4 z = {0.f, 0.f, 0.f, 0.f};
  for (; i < n4; i += st) ((float4*)p)[i] = z;
}

__global__ void k_zero_accum(float* accum)
{
  if (threadIdx.x < 2) accum[threadIdx.x] = 0.f;
}

// accum[1] += sum(M)
__global__ void k_sum(const float* __restrict__ M, size_t n4, float* __restrict__ accum)
{
  __shared__ float red[256];
  float s = 0.f;
  for (size_t i = (size_t)blockIdx.x * blockDim.x + threadIdx.x; i < n4;
       i += (size_t)gridDim.x * blockDim.x) {
    const float4 v = ((const float4*)M)[i];
    s += v.x + v.y + v.z + v.w;
  }
  red[threadIdx.x] = s;
  __syncthreads();
  for (int st = 128; st > 0; st >>= 1) {
    if (threadIdx.x < st) red[threadIdx.x] += red[threadIdx.x + st];
    __syncthreads();
  }
  if (threadIdx.x == 0) atomicAdd(accum + 1, red[0]);
}

__global__ void k_final(const float* __restrict__ accum, float* __restrict__ out)
{
  out[0] = accum[0];
  out[1] = accum[0] / accum[1];
}

// ---------------------------------------------------------------------------
extern "C" void kernel_launch(void* const* d_in, const int* in_sizes, int n_in,
                              void* d_out, int out_size, void* d_ws, size_t ws_size,
                              hipStream_t stream)
{
  const float* X    = (const float*)d_in[0];
  const float* M    = (const float*)d_in[1];
  const int*   bidx = (const int*)d_in[2];
  const float* W_ih = (const float*)d_in[3];
  const float* b_ih = (const float*)d_in[4];
  const float* W_hh = (const float*)d_in[5];
  const float* b_hh = (const float*)d_in[6];
  const float* Wo1  = (const float*)d_in[7];
  const float* bo1  = (const float*)d_in[8];
  const float* Wo2  = (const float*)d_in[9];
  const float* bo2  = (const float*)d_in[10];
  const float* Wp1  = (const float*)d_in[11];
  const float* bp1  = (const float*)d_in[12];
  const float* Wp2  = (const float*)d_in[13];
  const float* bp2  = (const float*)d_in[14];
  float* out = (float*)d_out;

  // Workspace layout (floats): h[NS*HS] | tmp[NS*HS] | accum[2]
  float* h     = (float*)d_ws;
  float* tmp   = h + (size_t)NS * HS;
  float* accum = tmp + (size_t)NS * HS;
  float* tmpE  = tmp;                       // [ES*HS]  (tmp reused: dead there)
  float* hnewE = tmp + (size_t)ES * HS;     // [ES*HS]

  k_zero<<<8192, 256, 0, stream>>>(h, (size_t)NS * HS / 4);
  k_zero_accum<<<1, 64, 0, stream>>>(accum);
  k_sum<<<2048, 256, 0, stream>>>(M, (size_t)KOBS * ES * DS / 4, accum);

  const dim3 gE(NS / 64, HS / 64);  // Euler GEMMs over all N rows
  const dim3 gP(ES / 64, HS / 64);  // E-row GEMMs, HS cols
  const dim3 gL(ES / 64, DS / 64);  // E-row GEMM, DS cols

  for (int k = 0; k < KOBS; ++k) {
    const int*   idx = bidx + (size_t)k * ES;
    const float* Xk  = X + (size_t)k * ES * DS;
    const float* Mk  = M + (size_t)k * ES * DS;

    for (int s = 0; s < 2; ++s) {   // STEPS_PER_OBS Euler steps
      k_gemm_tanh <<<gE, 256, 0, stream>>>(h, Wo1, bo1, tmp);
      k_gemm_resid<<<gE, 256, 0, stream>>>(tmp, Wo2, bo2, h);
    }
    k_gemm_relu_gather<<<gP, 256, 0, stream>>>(h, idx, Wp1, bp1, tmpE);
    k_gemm_loss<<<gL, 256, 0, stream>>>(tmpE, Wp2, bp2, Xk, Mk, accum);
    k_gemm_rnn<<<gP, 256, 0, stream>>>(Xk, h, idx, W_ih, b_ih, W_hh, b_hh, hnewE);
    k_scatter<<<2048, 256, 0, stream>>>(h, hnewE, idx);
  }
  // prop_to_end extra Euler steps do not affect the returned loss -> skipped.

  k_final<<<1, 1, 0, stream>>>(accum, out);
}

// Round 2
// 5418.650 us; speedup vs baseline: 4.9745x; 4.9745x over previous
//
#include <hip/hip_runtime.h>
#include <hip/hip_bf16.h>
#include <cstddef>
#include <cstdint>

#define NS   16384
#define HS   512
#define DS   128
#define KOBS 40
#define ES   4096
#define DTC  0.05f

typedef __bf16 bf16x8 __attribute__((ext_vector_type(8)));
typedef float  f32x4  __attribute__((ext_vector_type(4)));
typedef __hip_bfloat16 bf16_t;

// ---------------------------------------------------------------------------
// async 16B global->LDS (dest must be wave-uniform base + lane*16; our layout is)
// ---------------------------------------------------------------------------
__device__ __forceinline__ void async16(const void* g, void* l)
{
  __builtin_amdgcn_global_load_lds(
      (const __attribute__((address_space(1))) unsigned int*)g,
      (__attribute__((address_space(3))) unsigned int*)l, 16, 0, 0);
}

// ---------------------------------------------------------------------------
// One BK=32 compute step: 4 waves, each 64x64 quadrant as 4x4 mfma tiles.
// As/Bs: row-major [128][32] bf16, unpadded (global_load_lds layout).
// A-frag: lane holds A[m=lane&15][k=(lane>>4)*8 + 0..7]
// B-frag: lane holds W[n=lane&15][k=(lane>>4)*8 + 0..7]   (B^T input)
// C/D   : col=lane&15, row=(lane>>4)*4 + reg
// ---------------------------------------------------------------------------
__device__ __forceinline__ void mfma_step(
    f32x4 acc[4][4], const bf16_t* As, const bf16_t* Bs, int wave, int lane)
{
  const int q  = lane >> 4, ln = lane & 15;
  const int wr = (wave >> 1) * 64, wc = (wave & 1) * 64;
  bf16x8 a[4], b[4];
#pragma unroll
  for (int i = 0; i < 4; ++i)
    a[i] = *(const bf16x8*)(As + (wr + i * 16 + ln) * 32 + q * 8);
#pragma unroll
  for (int j = 0; j < 4; ++j)
    b[j] = *(const bf16x8*)(Bs + (wc + j * 16 + ln) * 32 + q * 8);
#pragma unroll
  for (int i = 0; i < 4; ++i)
#pragma unroll
    for (int j = 0; j < 4; ++j)
      acc[i][j] = __builtin_amdgcn_mfma_f32_16x16x32_bf16(a[i], b[j], acc[i][j], 0, 0, 0);
}

// ---------------------------------------------------------------------------
// K-loop: C[128,128] += A[rows(row0..+128), K] @ W[cols(col0..+128), K]^T
// A optionally gathered through idx. All bf16, k contiguous.
// ---------------------------------------------------------------------------
__device__ __forceinline__ void mfma_loop(
    f32x4 acc[4][4],
    const bf16_t* __restrict__ A, int lda, const int* __restrict__ idx, int row0,
    const bf16_t* __restrict__ W, int ldw, int col0, int K,
    bf16_t* As, bf16_t* Bs)
{
  const int tid = threadIdx.x, wave = tid >> 6, lane = tid & 63;
  const int srow = wave * 16 + (lane >> 2);   // 0..63
  const int skc  = (lane & 3) * 8;            // bf16 offset in 32-k tile
  int ar0 = row0 + srow, ar1 = row0 + srow + 64;
  if (idx) { ar0 = idx[ar0]; ar1 = idx[ar1]; }
  const bf16_t* Ap0 = A + (size_t)ar0 * lda + skc;
  const bf16_t* Ap1 = A + (size_t)ar1 * lda + skc;
  const bf16_t* Bp0 = W + (size_t)(col0 + srow) * ldw + skc;
  const bf16_t* Bp1 = W + (size_t)(col0 + srow + 64) * ldw + skc;
  bf16_t* lA0 = As + srow * 32 + skc;
  bf16_t* lA1 = As + (srow + 64) * 32 + skc;
  bf16_t* lB0 = Bs + srow * 32 + skc;
  bf16_t* lB1 = Bs + (srow + 64) * 32 + skc;

  for (int k0 = 0; k0 < K; k0 += 32) {
    __syncthreads();                       // LDS free (prev reads drained)
    async16(Ap0 + k0, lA0);
    async16(Ap1 + k0, lA1);
    async16(Bp0 + k0, lB0);
    async16(Bp1 + k0, lB1);
    __syncthreads();                       // vmcnt(0) + barrier
    mfma_step(acc, As, Bs, wave, lane);
  }
}

#define GEMM_PROLOGUE                                                        \
  __shared__ bf16_t As[128 * 32], Bs[128 * 32];                              \
  f32x4 acc[4][4];                                                           \
  _Pragma("unroll") for (int i = 0; i < 4; ++i)                              \
  _Pragma("unroll") for (int j = 0; j < 4; ++j)                              \
      acc[i][j] = (f32x4){0.f, 0.f, 0.f, 0.f};                               \
  const int tid = threadIdx.x, wave = tid >> 6, lane = tid & 63;             \
  const int q = lane >> 4, ln = lane & 15;                                   \
  const int wr = (wave >> 1) * 64, wc = (wave & 1) * 64;                     \
  const int row0 = blockIdx.x * 128, col0 = blockIdx.y * 128;                \
  (void)tid;

// ---------------------------------------------------------------------------
// Kernels
// ---------------------------------------------------------------------------

// tmp = tanh(h @ Wo1^T + bo1)
__global__ __launch_bounds__(256) void k_gemm_tanh(
    const bf16_t* __restrict__ A, const bf16_t* __restrict__ W,
    const float* __restrict__ bias, bf16_t* __restrict__ out)
{
  GEMM_PROLOGUE
  mfma_loop(acc, A, HS, nullptr, row0, W, HS, col0, HS, As, Bs);
#pragma unroll
  for (int j = 0; j < 4; ++j) {
    const int c = col0 + wc + j * 16 + ln;
    const float bj = bias[c];
#pragma unroll
    for (int i = 0; i < 4; ++i)
#pragma unroll
      for (int r = 0; r < 4; ++r) {
        const int rw = row0 + wr + i * 16 + q * 4 + r;
        out[(size_t)rw * HS + c] = __float2bfloat16(tanhf(acc[i][j][r] + bj));
      }
  }
}

// h = h + DT * (tmp @ Wo2^T + bo2)
__global__ __launch_bounds__(256) void k_gemm_resid(
    const bf16_t* __restrict__ A, const bf16_t* __restrict__ W,
    const float* __restrict__ bias, bf16_t* __restrict__ h)
{
  GEMM_PROLOGUE
  mfma_loop(acc, A, HS, nullptr, row0, W, HS, col0, HS, As, Bs);
#pragma unroll
  for (int j = 0; j < 4; ++j) {
    const int c = col0 + wc + j * 16 + ln;
    const float bj = bias[c];
#pragma unroll
    for (int i = 0; i < 4; ++i)
#pragma unroll
      for (int r = 0; r < 4; ++r) {
        const int rw = row0 + wr + i * 16 + q * 4 + r;
        const size_t o = (size_t)rw * HS + c;
        const float hv = __bfloat162float(h[o]) + DTC * (acc[i][j][r] + bj);
        h[o] = __float2bfloat16(hv);
      }
  }
}

// tmpE = relu(h[idx] @ Wp1^T + bp1)
__global__ __launch_bounds__(256) void k_gemm_relu(
    const bf16_t* __restrict__ h, const int* __restrict__ idx,
    const bf16_t* __restrict__ W, const float* __restrict__ bias,
    bf16_t* __restrict__ out)
{
  GEMM_PROLOGUE
  mfma_loop(acc, h, HS, idx, row0, W, HS, col0, HS, As, Bs);
#pragma unroll
  for (int j = 0; j < 4; ++j) {
    const int c = col0 + wc + j * 16 + ln;
    const float bj = bias[c];
#pragma unroll
    for (int i = 0; i < 4; ++i)
#pragma unroll
      for (int r = 0; r < 4; ++r) {
        const int rw = row0 + wr + i * 16 + q * 4 + r;
        const float v = acc[i][j][r] + bj;
        out[(size_t)rw * HS + c] = __float2bfloat16(v > 0.f ? v : 0.f);
      }
  }
}

// p = tmpE @ Wp2^T + bp2 ; loss += sum |X - p| * M
__global__ __launch_bounds__(256) void k_gemm_loss(
    const bf16_t* __restrict__ A, const bf16_t* __restrict__ W,
    const float* __restrict__ bias, const float* __restrict__ X,
    const float* __restrict__ Mm, float* __restrict__ accum)
{
  GEMM_PROLOGUE
  mfma_loop(acc, A, HS, nullptr, row0, W, HS, col0, HS, As, Bs);
  float ls = 0.f;
#pragma unroll
  for (int j = 0; j < 4; ++j) {
    const int c = col0 + wc + j * 16 + ln;
    const float bj = bias[c];
#pragma unroll
    for (int i = 0; i < 4; ++i)
#pragma unroll
      for (int r = 0; r < 4; ++r) {
        const int rw = row0 + wr + i * 16 + q * 4 + r;
        const float p = acc[i][j][r] + bj;
        const size_t o = (size_t)rw * DS + c;
        ls += fabsf(X[o] - p) * Mm[o];
      }
  }
#pragma unroll
  for (int off = 32; off > 0; off >>= 1) ls += __shfl_down(ls, off);
  __shared__ float red[4];
  if (lane == 0) red[wave] = ls;
  __syncthreads();
  if (tid == 0) atomicAdd(accum, red[0] + red[1] + red[2] + red[3]);
}

// hnewE = tanh(Xk @ W_ih^T + b_ih + h[idx] @ W_hh^T + b_hh)
__global__ __launch_bounds__(256) void k_gemm_rnn(
    const float* __restrict__ Xk, const bf16_t* __restrict__ h,
    const int* __restrict__ idx,
    const bf16_t* __restrict__ Wih, const float* __restrict__ b_ih,
    const bf16_t* __restrict__ Whh, const float* __restrict__ b_hh,
    bf16_t* __restrict__ outE)
{
  GEMM_PROLOGUE
  // ---- phase 1: K=DS, A = cvt(Xk) manual staging, B = Wih async ----
  {
    const int srow = wave * 16 + (lane >> 2);
    const int skc  = (lane & 3) * 8;
    const bf16_t* Bp0 = Wih + (size_t)(col0 + srow) * DS + skc;
    const bf16_t* Bp1 = Wih + (size_t)(col0 + srow + 64) * DS + skc;
    bf16_t* lB0 = Bs + srow * 32 + skc;
    bf16_t* lB1 = Bs + (srow + 64) * 32 + skc;
    const int xr = tid >> 1, xh = (tid & 1) * 16;
    for (int k0 = 0; k0 < DS; k0 += 32) {
      __syncthreads();
      async16(Bp0 + k0, lB0);
      async16(Bp1 + k0, lB1);
      {
        const float* s = Xk + (size_t)(row0 + xr) * DS + k0 + xh;
        __attribute__((aligned(16))) bf16_t buf[16];
#pragma unroll
        for (int u = 0; u < 16; ++u) buf[u] = __float2bfloat16(s[u]);
        *(uint4*)(As + xr * 32 + xh)     = *(const uint4*)buf;
        *(uint4*)(As + xr * 32 + xh + 8) = *(const uint4*)(buf + 8);
      }
      __syncthreads();
      mfma_step(acc, As, Bs, wave, lane);
    }
  }
  // ---- phase 2: K=HS, A = h[idx] async gather, B = Whh ----
  mfma_loop(acc, h, HS, idx, row0, Whh, HS, col0, HS, As, Bs);
#pragma unroll
  for (int j = 0; j < 4; ++j) {
    const int c = col0 + wc + j * 16 + ln;
    const float bj = b_ih[c] + b_hh[c];
#pragma unroll
    for (int i = 0; i < 4; ++i)
#pragma unroll
      for (int r = 0; r < 4; ++r) {
        const int rw = row0 + wr + i * 16 + q * 4 + r;
        outE[(size_t)rw * HS + c] = __float2bfloat16(tanhf(acc[i][j][r] + bj));
      }
  }
}

// h[idx[r], :] = src[r, :]   (bf16, 8 elems = 16B per thread)
__global__ void k_scatter(bf16_t* __restrict__ h, const bf16_t* __restrict__ src,
                          const int* __restrict__ idx)
{
  const int t  = blockIdx.x * 256 + threadIdx.x;   // ES * (HS/8) threads
  const int r  = t >> 6;
  const int c8 = (t & 63) * 8;
  const int gr = idx[r];
  *(uint4*)(h + (size_t)gr * HS + c8) = *(const uint4*)(src + (size_t)r * HS + c8);
}

__global__ void k_cvt(const float* __restrict__ s, bf16_t* __restrict__ d, int n)
{
  const int i = blockIdx.x * 256 + threadIdx.x;    // over n/4 float4s
  if (i * 4 < n) {
    const float4 v = ((const float4*)s)[i];
    d[i * 4 + 0] = __float2bfloat16(v.x);
    d[i * 4 + 1] = __float2bfloat16(v.y);
    d[i * 4 + 2] = __float2bfloat16(v.z);
    d[i * 4 + 3] = __float2bfloat16(v.w);
  }
}

__global__ void k_zero(float* __restrict__ p, size_t n4)
{
  size_t i = (size_t)blockIdx.x * blockDim.x + threadIdx.x;
  const size_t st = (size_t)gridDim.x * blockDim.x;
  const float4 z = {0.f, 0.f, 0.f, 0.f};
  for (; i < n4; i += st) ((float4*)p)[i] = z;
}

__global__ void k_zero_accum(float* accum)
{
  if (threadIdx.x < 2) accum[threadIdx.x] = 0.f;
}

__global__ void k_sum(const float* __restrict__ M, size_t n4, float* __restrict__ accum)
{
  __shared__ float red[256];
  float s = 0.f;
  for (size_t i = (size_t)blockIdx.x * blockDim.x + threadIdx.x; i < n4;
       i += (size_t)gridDim.x * blockDim.x) {
    const float4 v = ((const float4*)M)[i];
    s += v.x + v.y + v.z + v.w;
  }
  red[threadIdx.x] = s;
  __syncthreads();
  for (int st = 128; st > 0; st >>= 1) {
    if (threadIdx.x < st) red[threadIdx.x] += red[threadIdx.x + st];
    __syncthreads();
  }
  if (threadIdx.x == 0) atomicAdd(accum + 1, red[0]);
}

__global__ void k_final(const float* __restrict__ accum, float* __restrict__ out)
{
  out[0] = accum[0];
  out[1] = accum[0] / accum[1];
}

// ---------------------------------------------------------------------------
extern "C" void kernel_launch(void* const* d_in, const int* in_sizes, int n_in,
                              void* d_out, int out_size, void* d_ws, size_t ws_size,
                              hipStream_t stream)
{
  const float* X    = (const float*)d_in[0];
  const float* M    = (const float*)d_in[1];
  const int*   bidx = (const int*)d_in[2];
  const float* W_ih = (const float*)d_in[3];
  const float* b_ih = (const float*)d_in[4];
  const float* W_hh = (const float*)d_in[5];
  const float* b_hh = (const float*)d_in[6];
  const float* Wo1  = (const float*)d_in[7];
  const float* bo1  = (const float*)d_in[8];
  const float* Wo2  = (const float*)d_in[9];
  const float* bo2  = (const float*)d_in[10];
  const float* Wp1  = (const float*)d_in[11];
  const float* bp1  = (const float*)d_in[12];
  const float* Wp2  = (const float*)d_in[13];
  const float* bp2  = (const float*)d_in[14];
  float* out = (float*)d_out;

  // ws layout (bytes): h 16MB | tmp 16MB | tmpE 4MB | hnewE 4MB | weights | accum
  char* w = (char*)d_ws;
  bf16_t* h     = (bf16_t*)w;                         w += (size_t)NS * HS * 2;
  bf16_t* tmp   = (bf16_t*)w;                         w += (size_t)NS * HS * 2;
  bf16_t* tmpE  = (bf16_t*)w;                         w += (size_t)ES * HS * 2;
  bf16_t* hnewE = (bf16_t*)w;                         w += (size_t)ES * HS * 2;
  bf16_t* wWo1  = (bf16_t*)w;                         w += (size_t)HS * HS * 2;
  bf16_t* wWo2  = (bf16_t*)w;                         w += (size_t)HS * HS * 2;
  bf16_t* wWp1  = (bf16_t*)w;                         w += (size_t)HS * HS * 2;
  bf16_t* wWp2  = (bf16_t*)w;                         w += (size_t)DS * HS * 2;
  bf16_t* wWih  = (bf16_t*)w;                         w += (size_t)HS * DS * 2;
  bf16_t* wWhh  = (bf16_t*)w;                         w += (size_t)HS * HS * 2;
  float*  accum = (float*)w;

  // setup: zero h + accum, total mask sum, weight conversions
  k_zero<<<2048, 256, 0, stream>>>((float*)h, (size_t)NS * HS * 2 / 16);
  k_zero_accum<<<1, 64, 0, stream>>>(accum);
  k_sum<<<2048, 256, 0, stream>>>(M, (size_t)KOBS * ES * DS / 4, accum);
  k_cvt<<<256, 256, 0, stream>>>(Wo1, wWo1, HS * HS);
  k_cvt<<<256, 256, 0, stream>>>(Wo2, wWo2, HS * HS);
  k_cvt<<<256, 256, 0, stream>>>(Wp1, wWp1, HS * HS);
  k_cvt<<<64, 256, 0, stream>>>(Wp2, wWp2, DS * HS);
  k_cvt<<<64, 256, 0, stream>>>(W_ih, wWih, HS * DS);
  k_cvt<<<256, 256, 0, stream>>>(W_hh, wWhh, HS * HS);

  const dim3 gE(NS / 128, HS / 128);  // 128 x 4
  const dim3 gP(ES / 128, HS / 128);  // 32 x 4
  const dim3 gL(ES / 128, DS / 128);  // 32 x 1

  for (int k = 0; k < KOBS; ++k) {
    const int*   idx = bidx + (size_t)k * ES;
    const float* Xk  = X + (size_t)k * ES * DS;
    const float* Mk  = M + (size_t)k * ES * DS;

    for (int s = 0; s < 2; ++s) {
      k_gemm_tanh <<<gE, 256, 0, stream>>>(h, wWo1, bo1, tmp);
      k_gemm_resid<<<gE, 256, 0, stream>>>(tmp, wWo2, bo2, h);
    }
    k_gemm_relu<<<gP, 256, 0, stream>>>(h, idx, wWp1, bp1, tmpE);
    k_gemm_loss<<<gL, 256, 0, stream>>>(tmpE, wWp2, bp2, Xk, Mk, accum);
    k_gemm_rnn <<<gP, 256, 0, stream>>>(Xk, h, idx, wWih, b_ih, wWhh, b_hh, hnewE);
    k_scatter<<<ES * (HS / 8) / 256, 256, 0, stream>>>(h, hnewE, idx);
  }
  // prop_to_end Euler steps don't affect outputs -> skipped.

  k_final<<<1, 1, 0, stream>>>(accum, out);
}